// Round 1
// baseline (33.216 us; speedup 1.0000x reference)
//
#include <hip/hip_runtime.h>
#include <hip/hip_bf16.h>

typedef __attribute__((ext_vector_type(8))) short bf16x8;
typedef __attribute__((ext_vector_type(4))) float f32x4;
typedef unsigned short u16;

static __device__ __forceinline__ u16 f2bf(float f) {
  unsigned u = __builtin_bit_cast(unsigned, f);
  return (u16)((u + 0x7fffu + ((u >> 16) & 1u)) >> 16);
}

// ---------------- precompute stage 1: T1 (input side), U1 (output side) -------------
// T1[r1][j1][i1][i0] = sum_r0 W1[j1,i1*16+r0] * W0[r0*16+r1, i0]      (16,16,8,4)
// U1[kh][j5][j3]     = sum_kl W5[j5,kl] * W4[kh*16+kl, j3]            (4,128,16)
__global__ void trl_p1(const float* __restrict__ W0, const float* __restrict__ W1,
                       const float* __restrict__ W4, const float* __restrict__ W5,
                       float* __restrict__ T1, float* __restrict__ U1) {
  int gid = blockIdx.x * 256 + threadIdx.x;  // 16384 threads
  if (gid < 8192) {
    int i0 = gid & 3, i1 = (gid >> 2) & 7, j1 = (gid >> 5) & 15, r1 = gid >> 9;
    float s = 0.f;
#pragma unroll
    for (int r0 = 0; r0 < 16; ++r0)
      s += W1[j1 * 128 + i1 * 16 + r0] * W0[(r0 * 16 + r1) * 4 + i0];
    T1[gid] = s;
  } else {
    int g = gid - 8192;
    int j3 = g & 15, j5 = (g >> 4) & 127, kh = g >> 11;
    float s = 0.f;
#pragma unroll
    for (int kl = 0; kl < 16; ++kl)
      s += W5[j5 * 16 + kl] * W4[(kh * 16 + kl) * 16 + j3];
    U1[g] = s;
  }
}

// ---------------- precompute stage 2: T2, U2 -------------
// T2[r1][j2][i2][i1][i0] = sum_j1 W2[j2,i2*16+j1]*T1[r1][j1][i1][i0]   (16,16,8,8,4)
// U2[kh][j5h][j6][j3]    = sum_j5l W6[j6,j5l]*U1[kh][j5h*16+j5l][j3]   (4,8,128,16)
__global__ void trl_p2(const float* __restrict__ W2, const float* __restrict__ W6,
                       const float* __restrict__ T1, const float* __restrict__ U1,
                       float* __restrict__ T2, float* __restrict__ U2) {
  int gid = blockIdx.x * 256 + threadIdx.x;  // 131072 threads
  if (gid < 65536) {
    int i0 = gid & 3, i1 = (gid >> 2) & 7, i2 = (gid >> 5) & 7, j2 = (gid >> 8) & 15, r1 = gid >> 12;
    float s = 0.f;
#pragma unroll
    for (int j1 = 0; j1 < 16; ++j1)
      s += W2[j2 * 128 + i2 * 16 + j1] * T1[((r1 * 16 + j1) * 8 + i1) * 4 + i0];
    T2[gid] = s;
  } else {
    int g = gid - 65536;
    int j3 = g & 15, j6 = (g >> 4) & 127, j5h = (g >> 11) & 7, kh = g >> 14;
    float s = 0.f;
#pragma unroll
    for (int j5l = 0; j5l < 16; ++j5l)
      s += W6[j6 * 16 + j5l] * U1[(kh * 128 + j5h * 16 + j5l) * 16 + j3];
    U2[g] = s;
  }
}

// ---------------- precompute stage 3: Apre (bf16), Bmat (bf16), x -> bf16 -------------
// Apre[p=r1*16+j3][i=i0*256+i1*32+i2*4+i3] = sum_j2 W3[j3,i3*16+j2]*T2[r1][j2][i2][i1][i0]
// Bmat[o][p=r1*16+j3] = sum_d W7[m7, r1*16+d] * U2[kh][j5h][j6h*16+d][j3],
//   o = kh*256 + j5h*32 + j6h*4 + m7
__global__ void trl_p3(const float* __restrict__ W3, const float* __restrict__ W7,
                       const float* __restrict__ T2, const float* __restrict__ U2,
                       const float* __restrict__ x,
                       u16* __restrict__ Apre, u16* __restrict__ Bmat, u16* __restrict__ xb) {
  int gid = blockIdx.x * 256 + threadIdx.x;  // 262144 threads
  {
    int i = gid & 1023, p = gid >> 10;
    int r1 = p >> 4, j3 = p & 15;
    int i0 = i >> 8, i1 = (i >> 5) & 7, i2 = (i >> 2) & 7, i3 = i & 3;
    float s = 0.f;
#pragma unroll
    for (int j2 = 0; j2 < 16; ++j2)
      s += W3[j3 * 64 + i3 * 16 + j2] * T2[(((r1 * 16 + j2) * 8 + i2) * 8 + i1) * 4 + i0];
    Apre[gid] = f2bf(s);
  }
  {
    int p = gid & 255, o = gid >> 8;
    int r1 = p >> 4, j3 = p & 15;
    int m7 = o & 3, j6h = (o >> 2) & 7, j5h = (o >> 5) & 7, kh = o >> 8;
    float s = 0.f;
#pragma unroll
    for (int d = 0; d < 16; ++d)
      s += W7[m7 * 256 + r1 * 16 + d] * U2[((kh * 8 + j5h) * 128 + j6h * 16 + d) * 16 + j3];
    Bmat[gid] = f2bf(s);
  }
  {
    const float4 v = reinterpret_cast<const float4*>(x)[gid];
    ushort4 o4;
    o4.x = f2bf(v.x); o4.y = f2bf(v.y); o4.z = f2bf(v.z); o4.w = f2bf(v.w);
    reinterpret_cast<ushort4*>(xb)[gid] = o4;
  }
}

// ---------------- bt-GEMM: C[M,N] = A[M,K] * B[N,K]^T  (bf16 in, f32 accum) -------------
// 64x64 block tile, BK=64, 4 waves as 2x2 (each 32x32), mfma_f32_16x16x32_bf16.
// LDS tiles [64 rows][64 k] bf16 (128B rows); global source pre-swizzled g^=(row&7)
// so linear global_load_lds dest + swizzled ds_read_b128 is bank-conflict-free.
template <int N, int K, bool BF16OUT>
__global__ __launch_bounds__(256) void gemm_bt(const u16* __restrict__ A,
                                               const u16* __restrict__ B,
                                               void* __restrict__ Cout,
                                               const float* __restrict__ bias) {
  __shared__ u16 As[64 * 64];
  __shared__ u16 Bs[64 * 64];
  const int tid = threadIdx.x;
  const int wave = tid >> 6;
  const int lane = tid & 63;
  const int m0 = blockIdx.y * 64;
  const int n0 = blockIdx.x * 64;
  const int wm = wave >> 1, wn = wave & 1;
  const int lrow = lane >> 3;  // staging: row within wave's 8-row slab
  const int lg = lane & 7;     // staging: 16B granule within 128B row
  const int l15 = lane & 15;
  const int l4 = lane >> 4;

  f32x4 acc[2][2] = {};

  for (int kt = 0; kt < K / 64; ++kt) {
#pragma unroll
    for (int q = 0; q < 2; ++q) {
      const int row = q * 32 + wave * 8 + lrow;
      const int gsrc = lg ^ (row & 7);
      const u16* ga = A + (size_t)(m0 + row) * K + kt * 64 + gsrc * 8;
      const u16* gb = B + (size_t)(n0 + row) * K + kt * 64 + gsrc * 8;
      u16* la = &As[(q * 32 + wave * 8) * 64];
      u16* lb = &Bs[(q * 32 + wave * 8) * 64];
      __builtin_amdgcn_global_load_lds((const __attribute__((address_space(1))) void*)ga,
                                       (__attribute__((address_space(3))) void*)la, 16, 0, 0);
      __builtin_amdgcn_global_load_lds((const __attribute__((address_space(1))) void*)gb,
                                       (__attribute__((address_space(3))) void*)lb, 16, 0, 0);
    }
    __syncthreads();

    bf16x8 af[2][2], bfr[2][2];
#pragma unroll
    for (int fm = 0; fm < 2; ++fm)
#pragma unroll
      for (int kk = 0; kk < 2; ++kk) {
        const int row = wm * 32 + fm * 16 + l15;
        const int gw = kk * 4 + l4;
        af[fm][kk] = *(const bf16x8*)&As[row * 64 + ((gw ^ (row & 7)) * 8)];
      }
#pragma unroll
    for (int fn = 0; fn < 2; ++fn)
#pragma unroll
      for (int kk = 0; kk < 2; ++kk) {
        const int row = wn * 32 + fn * 16 + l15;
        const int gw = kk * 4 + l4;
        bfr[fn][kk] = *(const bf16x8*)&Bs[row * 64 + ((gw ^ (row & 7)) * 8)];
      }
#pragma unroll
    for (int fm = 0; fm < 2; ++fm)
#pragma unroll
      for (int fn = 0; fn < 2; ++fn)
#pragma unroll
        for (int kk = 0; kk < 2; ++kk)
          acc[fm][fn] = __builtin_amdgcn_mfma_f32_16x16x32_bf16(af[fm][kk], bfr[fn][kk],
                                                                acc[fm][fn], 0, 0, 0);
    __syncthreads();
  }

  // epilogue: C/D layout col=lane&15, row=(lane>>4)*4+reg  [m89-verified]
#pragma unroll
  for (int fm = 0; fm < 2; ++fm)
#pragma unroll
    for (int fn = 0; fn < 2; ++fn) {
      const int gc = n0 + wn * 32 + fn * 16 + l15;
#pragma unroll
      for (int r = 0; r < 4; ++r) {
        const int gr = m0 + wm * 32 + fm * 16 + l4 * 4 + r;
        if constexpr (BF16OUT) {
          ((u16*)Cout)[(size_t)gr * N + gc] = f2bf(acc[fm][fn][r]);
        } else {
          ((float*)Cout)[(size_t)gr * N + gc] = acc[fm][fn][r] + bias[gc];
        }
      }
    }
}

extern "C" void kernel_launch(void* const* d_in, const int* in_sizes, int n_in,
                              void* d_out, int out_size, void* d_ws, size_t ws_size,
                              hipStream_t stream) {
  const float* x  = (const float*)d_in[0];
  const float* W0 = (const float*)d_in[1];
  const float* W1 = (const float*)d_in[2];
  const float* W2 = (const float*)d_in[3];
  const float* W3 = (const float*)d_in[4];
  const float* W4 = (const float*)d_in[5];
  const float* W5 = (const float*)d_in[6];
  const float* W6 = (const float*)d_in[7];
  const float* W7 = (const float*)d_in[8];
  const float* bias = (const float*)d_in[9];

  char* ws = (char*)d_ws;
  float* T1 = (float*)(ws + (0 << 10));      // 32 KB  (8192 f32)
  float* U1 = (float*)(ws + (32 << 10));     // 32 KB
  float* T2 = (float*)(ws + (64 << 10));     // 256 KB (65536 f32)
  float* U2 = (float*)(ws + (320 << 10));    // 256 KB
  u16* Apre = (u16*)(ws + (576 << 10));      // 512 KB (256x1024 bf16)
  u16* Bmat = (u16*)(ws + (1088 << 10));     // 512 KB (1024x256 bf16)
  u16* xb   = (u16*)(ws + (1600 << 10));     // 2 MB   (1024x1024 bf16)
  u16* Cb   = (u16*)(ws + (3648 << 10));     // 512 KB (1024x256 bf16)
  float* outp = (float*)d_out;

  trl_p1<<<64, 256, 0, stream>>>(W0, W1, W4, W5, T1, U1);
  trl_p2<<<512, 256, 0, stream>>>(W2, W6, T1, U1, T2, U2);
  trl_p3<<<1024, 256, 0, stream>>>(W3, W7, T2, U2, x, Apre, Bmat, xb);
  // C(1024x256) = xb(1024x1024) @ Apre(256x1024)^T
  gemm_bt<256, 1024, true><<<dim3(4, 16), 256, 0, stream>>>(xb, Apre, Cb, nullptr);
  // out(1024x1024) = Cb(1024x256) @ Bmat(1024x256)^T + bias
  gemm_bt<1024, 256, false><<<dim3(16, 16), 256, 0, stream>>>(Cb, Bmat, outp, bias);
}

// Round 2
// 25.783 us; speedup vs baseline: 1.2883x; 1.2883x over previous
//
#include <hip/hip_runtime.h>
#include <hip/hip_bf16.h>

typedef __attribute__((ext_vector_type(8))) short bf16x8;
typedef __attribute__((ext_vector_type(4))) float f32x4;
typedef unsigned short u16;

static __device__ __forceinline__ u16 f2bf(float f) {
  unsigned u = __builtin_bit_cast(unsigned, f);
  return (u16)((u + 0x7fffu + ((u >> 16) & 1u)) >> 16);
}

// ---------------- P1: pairwise core merges + x->bf16 ----------------
// T1[r1][j1][i1][i0] = sum_r0 W1[j1,i1*16+r0] * W0[r0*16+r1, i0]          (16,16,8,4)
// V1[j3][i3][i2][j1] = sum_j2 W3[j3,i3*16+j2] * W2[j2,i2*16+j1]           (16,4,8,16)
// U1[kh][j5][j3]     = sum_kl W5[j5,kl] * W4[kh*16+kl, j3]                (4,128,16)
// V2[m7][r1][j6h][j5l] = sum_d W7[m7,r1*16+d] * W6[j6h*16+d, j5l]         (4,16,8,16)
// xb = bf16(x)  (all 65536 threads, 4 float4 each)
__global__ __launch_bounds__(256) void trl_p1(
    const float* __restrict__ W0, const float* __restrict__ W1,
    const float* __restrict__ W2, const float* __restrict__ W3,
    const float* __restrict__ W4, const float* __restrict__ W5,
    const float* __restrict__ W6, const float* __restrict__ W7,
    const float* __restrict__ x,
    float* __restrict__ T1, float* __restrict__ V1,
    float* __restrict__ U1, float* __restrict__ V2,
    u16* __restrict__ xb) {
  const int gid = blockIdx.x * 256 + threadIdx.x;  // 65536 threads
  if (gid < 8192) {
    int i0 = gid & 3, i1 = (gid >> 2) & 7, j1 = (gid >> 5) & 15, r1 = gid >> 9;
    float s = 0.f;
#pragma unroll
    for (int r0 = 0; r0 < 16; ++r0)
      s += W1[j1 * 128 + i1 * 16 + r0] * W0[(r0 * 16 + r1) * 4 + i0];
    T1[gid] = s;
  } else if (gid < 16384) {
    int g = gid - 8192;
    int j1 = g & 15, i2 = (g >> 4) & 7, i3 = (g >> 7) & 3, j3 = g >> 9;
    float s = 0.f;
#pragma unroll
    for (int j2 = 0; j2 < 16; ++j2)
      s += W3[j3 * 64 + i3 * 16 + j2] * W2[j2 * 128 + i2 * 16 + j1];
    V1[g] = s;
  } else if (gid < 24576) {
    int g = gid - 16384;
    int j3 = g & 15, j5 = (g >> 4) & 127, kh = g >> 11;
    float s = 0.f;
#pragma unroll
    for (int kl = 0; kl < 16; ++kl)
      s += W5[j5 * 16 + kl] * W4[(kh * 16 + kl) * 16 + j3];
    U1[g] = s;
  } else {
    int g = gid - 24576;
    int j5l = g & 15, j6h = (g >> 4) & 7, r1 = (g >> 7) & 15, m7 = g >> 11;
    float s = 0.f;
#pragma unroll
    for (int d = 0; d < 16; ++d)
      s += W7[m7 * 256 + r1 * 16 + d] * W6[(j6h * 16 + d) * 16 + j5l];
    V2[g] = s;
  }
#pragma unroll
  for (int q = 0; q < 4; ++q) {
    const int c = gid + 65536 * q;
    const float4 v = reinterpret_cast<const float4*>(x)[c];
    ushort4 o4;
    o4.x = f2bf(v.x); o4.y = f2bf(v.y); o4.z = f2bf(v.z); o4.w = f2bf(v.w);
    reinterpret_cast<ushort4*>(xb)[c] = o4;
  }
}

// ---------------- P2: Apre (256x1024 bf16), Bmat (1024x256 bf16) ----------------
// Apre[p=r1*16+j3][i=i0*256+i1*32+i2*4+i3] = sum_j1 V1[j3][i3][i2][j1]*T1[r1][j1][i1][i0]
//   one thread: fixed (p, i1,i2,i3), vectorized over i0 (T1 innermost)
// Bmat[o][p=r1*16+j3] = sum_j5l V2[m7][r1][j6h][j5l]*U1[kh][j5h*16+j5l][j3]
//   one thread: fixed (o, r1, jq), vectorized over j3 chunk (U1 innermost)
__global__ __launch_bounds__(256) void trl_p2(
    const float* __restrict__ T1, const float* __restrict__ V1,
    const float* __restrict__ U1, const float* __restrict__ V2,
    u16* __restrict__ Apre, u16* __restrict__ Bmat) {
  const int gid = blockIdx.x * 256 + threadIdx.x;  // 131072 threads
  if (gid < 65536) {
    const int p = gid >> 8, irest = gid & 255;
    const int r1 = p >> 4, j3 = p & 15;
    const int i1 = irest >> 5, i2 = (irest >> 2) & 7, i3 = irest & 3;
    float4 a = make_float4(0.f, 0.f, 0.f, 0.f);
#pragma unroll
    for (int j1 = 0; j1 < 16; ++j1) {
      const float w = V1[((j3 * 4 + i3) * 8 + i2) * 16 + j1];
      const float4 t = reinterpret_cast<const float4*>(T1)[(r1 * 16 + j1) * 8 + i1];
      a.x += w * t.x; a.y += w * t.y; a.z += w * t.z; a.w += w * t.w;
    }
    Apre[p * 1024 + 0 * 256 + irest] = f2bf(a.x);
    Apre[p * 1024 + 1 * 256 + irest] = f2bf(a.y);
    Apre[p * 1024 + 2 * 256 + irest] = f2bf(a.z);
    Apre[p * 1024 + 3 * 256 + irest] = f2bf(a.w);
  } else {
    const int t = gid - 65536;
    const int o = t >> 6, rem = t & 63;
    const int r1 = rem >> 2, jq = rem & 3;
    const int m7 = o & 3, j6h = (o >> 2) & 7, j5h = (o >> 5) & 7, kh = o >> 8;
    float4 a = make_float4(0.f, 0.f, 0.f, 0.f);
#pragma unroll
    for (int j5l = 0; j5l < 16; ++j5l) {
      const float w = V2[((m7 * 16 + r1) * 8 + j6h) * 16 + j5l];
      const float4 u = reinterpret_cast<const float4*>(U1)[(kh * 128 + j5h * 16 + j5l) * 4 + jq];
      a.x += w * u.x; a.y += w * u.y; a.z += w * u.z; a.w += w * u.w;
    }
    ushort4 o4;
    o4.x = f2bf(a.x); o4.y = f2bf(a.y); o4.z = f2bf(a.z); o4.w = f2bf(a.w);
    *reinterpret_cast<ushort4*>(&Bmat[o * 256 + r1 * 16 + jq * 4]) = o4;
  }
}

// ---------------- G1: Cb(1024x256 bf16) = xb(1024x1024) @ Apre(256x1024)^T -------------
// 32x32 tile per block, 4 waves split K=1024 into 4x256; fragments direct from L2;
// one LDS reduce at the end. grid (8 n-tiles, 32 m-tiles).
__global__ __launch_bounds__(256) void trl_g1(const u16* __restrict__ A,
                                              const u16* __restrict__ B,
                                              u16* __restrict__ C) {
  __shared__ float red[3][32 * 33];
  const int tid = threadIdx.x;
  const int wave = tid >> 6, lane = tid & 63;
  const int l15 = lane & 15, l4 = lane >> 4;
  const int m0 = blockIdx.y * 32, n0 = blockIdx.x * 32;
  const int kbase = wave * 256;

  f32x4 acc[2][2] = {};
#pragma unroll
  for (int ks = 0; ks < 8; ++ks) {
    const int k = kbase + ks * 32 + l4 * 8;
    const bf16x8 a0 = *(const bf16x8*)&A[(size_t)(m0 + l15) * 1024 + k];
    const bf16x8 a1 = *(const bf16x8*)&A[(size_t)(m0 + 16 + l15) * 1024 + k];
    const bf16x8 b0 = *(const bf16x8*)&B[(size_t)(n0 + l15) * 1024 + k];
    const bf16x8 b1 = *(const bf16x8*)&B[(size_t)(n0 + 16 + l15) * 1024 + k];
    acc[0][0] = __builtin_amdgcn_mfma_f32_16x16x32_bf16(a0, b0, acc[0][0], 0, 0, 0);
    acc[0][1] = __builtin_amdgcn_mfma_f32_16x16x32_bf16(a0, b1, acc[0][1], 0, 0, 0);
    acc[1][0] = __builtin_amdgcn_mfma_f32_16x16x32_bf16(a1, b0, acc[1][0], 0, 0, 0);
    acc[1][1] = __builtin_amdgcn_mfma_f32_16x16x32_bf16(a1, b1, acc[1][1], 0, 0, 0);
  }

  if (wave > 0) {
#pragma unroll
    for (int fm = 0; fm < 2; ++fm)
#pragma unroll
      for (int fn = 0; fn < 2; ++fn)
#pragma unroll
        for (int r = 0; r < 4; ++r)
          red[wave - 1][(fm * 16 + l4 * 4 + r) * 33 + fn * 16 + l15] = acc[fm][fn][r];
  }
  __syncthreads();
  if (wave == 0) {
#pragma unroll
    for (int fm = 0; fm < 2; ++fm)
#pragma unroll
      for (int fn = 0; fn < 2; ++fn)
#pragma unroll
        for (int r = 0; r < 4; ++r) {
          const int row = fm * 16 + l4 * 4 + r, col = fn * 16 + l15;
          float s = acc[fm][fn][r] + red[0][row * 33 + col] + red[1][row * 33 + col] +
                    red[2][row * 33 + col];
          C[(size_t)(m0 + row) * 256 + n0 + col] = f2bf(s);
        }
  }
}

// ---------------- G2: out(1024x1024 f32) = Cb(1024x256) @ Bmat(1024x256)^T + bias -------
// Each wave owns a 32x32 tile (1024 tiles, 256 blocks x 4 waves). No LDS, no barriers.
__global__ __launch_bounds__(256) void trl_g2(const u16* __restrict__ A,
                                              const u16* __restrict__ B,
                                              const float* __restrict__ bias,
                                              float* __restrict__ out) {
  const int tid = threadIdx.x;
  const int wave = tid >> 6, lane = tid & 63;
  const int l15 = lane & 15, l4 = lane >> 4;
  const int tile = blockIdx.x * 4 + wave;
  const int m0 = (tile >> 5) * 32, n0 = (tile & 31) * 32;

  f32x4 acc[2][2] = {};
#pragma unroll
  for (int ks = 0; ks < 8; ++ks) {
    const int k = ks * 32 + l4 * 8;
    const bf16x8 a0 = *(const bf16x8*)&A[(size_t)(m0 + l15) * 256 + k];
    const bf16x8 a1 = *(const bf16x8*)&A[(size_t)(m0 + 16 + l15) * 256 + k];
    const bf16x8 b0 = *(const bf16x8*)&B[(size_t)(n0 + l15) * 256 + k];
    const bf16x8 b1 = *(const bf16x8*)&B[(size_t)(n0 + 16 + l15) * 256 + k];
    acc[0][0] = __builtin_amdgcn_mfma_f32_16x16x32_bf16(a0, b0, acc[0][0], 0, 0, 0);
    acc[0][1] = __builtin_amdgcn_mfma_f32_16x16x32_bf16(a0, b1, acc[0][1], 0, 0, 0);
    acc[1][0] = __builtin_amdgcn_mfma_f32_16x16x32_bf16(a1, b0, acc[1][0], 0, 0, 0);
    acc[1][1] = __builtin_amdgcn_mfma_f32_16x16x32_bf16(a1, b1, acc[1][1], 0, 0, 0);
  }

#pragma unroll
  for (int fn = 0; fn < 2; ++fn) {
    const int gc = n0 + fn * 16 + l15;
    const float bv = bias[gc];
#pragma unroll
    for (int fm = 0; fm < 2; ++fm)
#pragma unroll
      for (int r = 0; r < 4; ++r) {
        const int gr = m0 + fm * 16 + l4 * 4 + r;
        out[(size_t)gr * 1024 + gc] = acc[fm][fn][r] + bv;
      }
  }
}

extern "C" void kernel_launch(void* const* d_in, const int* in_sizes, int n_in,
                              void* d_out, int out_size, void* d_ws, size_t ws_size,
                              hipStream_t stream) {
  const float* x  = (const float*)d_in[0];
  const float* W0 = (const float*)d_in[1];
  const float* W1 = (const float*)d_in[2];
  const float* W2 = (const float*)d_in[3];
  const float* W3 = (const float*)d_in[4];
  const float* W4 = (const float*)d_in[5];
  const float* W5 = (const float*)d_in[6];
  const float* W6 = (const float*)d_in[7];
  const float* W7 = (const float*)d_in[8];
  const float* bias = (const float*)d_in[9];

  char* ws = (char*)d_ws;
  float* T1 = (float*)(ws + (0 << 10));       // 32 KB
  float* V1 = (float*)(ws + (32 << 10));      // 32 KB
  float* U1 = (float*)(ws + (64 << 10));      // 32 KB
  float* V2 = (float*)(ws + (96 << 10));      // 32 KB
  u16* Apre = (u16*)(ws + (128 << 10));       // 512 KB (256x1024)
  u16* Bmat = (u16*)(ws + (640 << 10));       // 512 KB (1024x256)
  u16* xb   = (u16*)(ws + (1152 << 10));      // 2 MB   (1024x1024)
  u16* Cb   = (u16*)(ws + (3200 << 10));      // 512 KB (1024x256)
  float* outp = (float*)d_out;

  trl_p1<<<256, 256, 0, stream>>>(W0, W1, W2, W3, W4, W5, W6, W7, x, T1, V1, U1, V2, xb);
  trl_p2<<<512, 256, 0, stream>>>(T1, V1, U1, V2, Apre, Bmat);
  trl_g1<<<dim3(8, 32), 256, 0, stream>>>(xb, Apre, Cb);
  trl_g2<<<256, 256, 0, stream>>>(Cb, Bmat, bias, outp);
}